// Round 4
// baseline (83.532 us; speedup 1.0000x reference)
//
#include <hip/hip_runtime.h>
#include <math.h>

#define BN 8192
#define DN 512
#define KN 8
#define WIN 8           // window half-width around sorted rank (== KN, exact by
                        // the sorted-order argument: 8 nearest are within +-8 ranks)

typedef unsigned long long u64;
typedef unsigned int u32;

// ---- ws layout (bytes) ----
// keys     : u64  [8192] @ 0        (fully sorted (label|idx) keys)
// partials : float[2048] @ 65536
#define OFF_KEYS  0
#define OFF_PART  65536

// Order-preserving float->uint transform (all floats).
__device__ __forceinline__ u32 flip_f32(u32 f) {
  return f ^ (u32)(((int)f >> 31) | 0x80000000);
}
__device__ __forceinline__ float unflip_f32(u32 f) {
  return __uint_as_float((f & 0x80000000u) ? (f ^ 0x80000000u) : ~f);
}

__device__ __forceinline__ u64 shfl_xor_u64(u64 v, int mask) {
  u32 lo = (u32)v, hi = (u32)(v >> 32);
  lo = (u32)__shfl_xor((int)lo, mask, 64);
  hi = (u32)__shfl_xor((int)hi, mask, 64);
  return ((u64)hi << 32) | lo;
}
__device__ __forceinline__ u64 shfl_u64(u64 v, int src) {
  u32 lo = (u32)v, hi = (u32)(v >> 32);
  lo = (u32)__shfl((int)lo, src, 64);
  hi = (u32)__shfl((int)hi, src, 64);
  return ((u64)hi << 32) | lo;
}

// ---------------------------------------------------------------------------
// Kernel A: brute-force rank sort + S cache-warm. 512 blocks x 256 threads.
// Ranking (proven R1): block stages all 8192 u64 keys in LDS, each wave ranks
// 4 elements by counting smaller keys, scatters keys[rank]=key. Exact sort,
// no atomics. NEW: each block also streams a 32 KB slice of S (block i ->
// rows [16i,16i+16)) into registers at kernel start — the harness's 268 MB
// workspace poison evicts S from L2/L3 every iteration, and ranksort's HBM
// is otherwise idle. Loads complete under the LDS ranking; asm keepalive
// prevents DCE. Warms all 16 MB of S into L2/L3 for kernel B.
// ---------------------------------------------------------------------------
__global__ __launch_bounds__(256) void ranksort_kernel(const float* __restrict__ L,
                                                       const float* __restrict__ S,
                                                       u64* __restrict__ keys_out) {
  __shared__ u64 kk[BN];                    // 64 KB
  const int tid  = threadIdx.x;
  const int lane = tid & 63;
  const int wv   = tid >> 6;                // 0..3

  // issue S-warm loads first: 256 threads x 8 float4 = 32 KB coalesced
  const float4* Sw = (const float4*)(S + (size_t)blockIdx.x * 16 * DN);
  float4 pre[8];
#pragma unroll
  for (int j = 0; j < 8; j++) pre[j] = Sw[tid + j * 256];

  // build keys (coalesced label loads; L2-resident after first blocks)
#pragma unroll
  for (int t = 0; t < BN / 256; t++) {
    const int i = tid + t * 256;
    kk[i] = ((u64)flip_f32(__float_as_uint(L[i])) << 32) | (u32)i;
  }
  __syncthreads();

  const int wave_g = blockIdx.x * 4 + wv;   // 0..2047
  const int e0 = wave_g * 4;                // 4 elements per wave
  const u64 k0 = kk[e0 + 0];                // broadcast reads (same addr)
  const u64 k1 = kk[e0 + 1];
  const u64 k2 = kk[e0 + 2];
  const u64 k3 = kk[e0 + 3];

  int c0 = 0, c1 = 0, c2 = 0, c3 = 0;
  // strided scan: lane l reads kk[l + 64t]
#pragma unroll 4
  for (int t = lane; t < BN; t += 64) {
    const u64 v = kk[t];
    c0 += (v < k0); c1 += (v < k1); c2 += (v < k2); c3 += (v < k3);
  }
#pragma unroll
  for (int off = 1; off < 64; off <<= 1) {
    c0 += __shfl_xor(c0, off, 64);
    c1 += __shfl_xor(c1, off, 64);
    c2 += __shfl_xor(c2, off, 64);
    c3 += __shfl_xor(c3, off, 64);
  }
  if (lane == 0) {                           // ranks are unique -> no conflicts
    keys_out[c0] = k0;
    keys_out[c1] = k1;
    keys_out[c2] = k2;
    keys_out[c3] = k3;
  }

  // keepalive: make the prefetched values observable so the loads survive.
#pragma unroll
  for (int j = 0; j < 8; j++) {
    asm volatile("" :: "v"(pre[j].x), "v"(pre[j].y), "v"(pre[j].z), "v"(pre[j].w));
  }
}

// ---------------------------------------------------------------------------
// Kernel B: 2048 blocks x 256 threads, 4 consecutive sorted ranks per block
// (one row per wave; xcd swizzle for L2 locality). Window is +-8 sorted ranks
// (17 candidates, lanes 0..16) -> 15-substep 32-wide bitonic (proven R2/R3).
// NEW latency schedule (R3 post-mortem: VGPR=32 showed the compiler
// serialized 8 dependent neighbor-row loads):
//   - self-row loads issue right after the lane-8 shuffle (before the
//     bitonic: ~250 cycles of free covering),
//   - ALL 16 neighbor float4 loads are hoisted into registers before the
//     weight computation and FMAs (one latency round-trip instead of 8).
// Static indices via full unroll keep nb[][] in VGPRs (no scratch).
// Contention-free tail: ONE partials store per block (R2 lesson: 2048-block
// same-address atomic fan-in costs ~60 us on non-coherent L2s).
// ---------------------------------------------------------------------------
__global__ __launch_bounds__(256, 4) void wmean_cos_kernel(const float* __restrict__ S,
                                                           const u64* __restrict__ keys,
                                                           float* __restrict__ partials) {
  const int tid  = threadIdx.x;
  const int lane = tid & 63;
  const int wv   = tid >> 6;                 // 0..3
  const int blk  = blockIdx.x;               // 0..2047
  const int xcd  = blk & 7;
  const int span = blk >> 3;                 // 0..255
  const int rr   = xcd * 1024 + span * 4 + wv;   // this wave's sorted rank

  // candidate window: ranks rr-8 .. rr+8 on lanes 0..16 (L2-resident 64KB)
  const int q = rr - WIN + lane;
  const bool inw = (lane <= 2 * WIN) && (q >= 0) && (q < BN);
  const u64 wk = inw ? keys[q] : ~0ull;

  const u64 ckey = shfl_u64(wk, WIN);        // lane 8 holds rank rr (valid)
  const float Lb = unflip_f32((u32)(ckey >> 32));
  const int   b  = (int)(u32)ckey;

  // self-row loads: address known now; bitonic below hides the latency
  const float4* Srow = (const float4*)(S + (size_t)b * DN);
  const float4 s0 = Srow[lane];
  const float4 s1 = Srow[lane + 64];

  u64 key = ~0ull;
  if (wk != ~0ull) {                         // real keys never equal ~0ull
    const float lab = unflip_f32((u32)(wk >> 32));
    const float dist = fabsf(lab - Lb);      // >=0: IEEE bits order-preserving
    key = ((u64)__float_as_uint(dist) << 32) | (u32)wk;
  }

  // 32-wide bitonic sort ascending (15 substeps); candidates in lower half,
  // lanes 17..31 padded with ~0ull. up=(lane&k)==0 holds for k=32 too.
#pragma unroll
  for (int k = 2; k <= 32; k <<= 1) {
#pragma unroll
    for (int j = 16; j > 0; j >>= 1) {
      if (j >= k) continue;
      const u64 o = shfl_xor_u64(key, j);
      const bool lower = (lane & j) == 0;
      const bool up = (lane & k) == 0;
      key = (up == lower) ? (key < o ? key : o) : (key < o ? o : key);
    }
  }

  // broadcast the 8 nearest indices, then ISSUE all neighbor loads before
  // any weight math — one L2/L3 round-trip covers all 8 rows.
  const int myidx = (int)(u32)key;
  int ix[KN];
#pragma unroll
  for (int k = 0; k < KN; k++) ix[k] = __shfl(myidx, k, 64);

  float4 nb0[KN], nb1[KN];
#pragma unroll
  for (int k = 0; k < KN; k++) {
    const float4* Nrow = (const float4*)(S + (size_t)ix[k] * DN);
    nb0[k] = Nrow[lane];
    nb1[k] = Nrow[lane + 64];
  }

  // normalized Gaussian weights (lanes 0..7), computed under the load shadow
  float e = 0.0f;
  if (lane < 8) {
    const float d = __uint_as_float((u32)(key >> 32));
    e = expf(-d * d * (1.0f / 50.0f));       // 2*STD^2 = 50; const cancels
  }
  float ssum = e;
  ssum += __shfl_xor(ssum, 1, 64);
  ssum += __shfl_xor(ssum, 2, 64);
  ssum += __shfl_xor(ssum, 4, 64);
  const float wn = e / ssum;

  float w[KN];
#pragma unroll
  for (int k = 0; k < KN; k++) w[k] = __shfl(wn, k, 64);

  float4 m0 = make_float4(0.f, 0.f, 0.f, 0.f);
  float4 m1 = make_float4(0.f, 0.f, 0.f, 0.f);
#pragma unroll
  for (int k = 0; k < KN; k++) {
    const float wk2 = w[k];
    m0.x = fmaf(wk2, nb0[k].x, m0.x); m0.y = fmaf(wk2, nb0[k].y, m0.y);
    m0.z = fmaf(wk2, nb0[k].z, m0.z); m0.w = fmaf(wk2, nb0[k].w, m0.w);
    m1.x = fmaf(wk2, nb1[k].x, m1.x); m1.y = fmaf(wk2, nb1[k].y, m1.y);
    m1.z = fmaf(wk2, nb1[k].z, m1.z); m1.w = fmaf(wk2, nb1[k].w, m1.w);
  }

  float dot = s0.x * m0.x + s0.y * m0.y + s0.z * m0.z + s0.w * m0.w
            + s1.x * m1.x + s1.y * m1.y + s1.z * m1.z + s1.w * m1.w;
  float ns  = s0.x * s0.x + s0.y * s0.y + s0.z * s0.z + s0.w * s0.w
            + s1.x * s1.x + s1.y * s1.y + s1.z * s1.z + s1.w * s1.w;
  float nm  = m0.x * m0.x + m0.y * m0.y + m0.z * m0.z + m0.w * m0.w
            + m1.x * m1.x + m1.y * m1.y + m1.z * m1.z + m1.w * m1.w;

#pragma unroll
  for (int off = 32; off > 0; off >>= 1) {
    dot += __shfl_down(dot, off, 64);
    ns  += __shfl_down(ns,  off, 64);
    nm  += __shfl_down(nm,  off, 64);
  }

  __shared__ float psim[4];
  if (lane == 0) {
    psim[wv] = dot / ((1e-10f + sqrtf(ns)) * (1e-10f + sqrtf(nm)));
  }
  __syncthreads();
  if (tid == 0) {
    partials[blk] = psim[0] + psim[1] + psim[2] + psim[3];
  }
}

// ---------------------------------------------------------------------------
// Kernel C: reduce 2048 partials -> out[0] = 1 - sum/8192.
// ---------------------------------------------------------------------------
__global__ __launch_bounds__(256) void finalize_kernel(const float* __restrict__ partials,
                                                       float* __restrict__ out) {
  const int tid = threadIdx.x;
  float s = 0.0f;
  for (int i = tid; i < 2048; i += 256) s += partials[i];
#pragma unroll
  for (int off = 32; off > 0; off >>= 1) s += __shfl_down(s, off, 64);
  __shared__ float ps[4];
  if ((tid & 63) == 0) ps[tid >> 6] = s;
  __syncthreads();
  if (tid == 0) {
    const float tot = ps[0] + ps[1] + ps[2] + ps[3];
    out[0] = 1.0f - tot * (1.0f / (float)BN);
  }
}

extern "C" void kernel_launch(void* const* d_in, const int* in_sizes, int n_in,
                              void* d_out, int out_size, void* d_ws, size_t ws_size,
                              hipStream_t stream) {
  const float* S = (const float*)d_in[0];  // Struct (8192 x 512) fp32
  const float* L = (const float*)d_in[1];  // Label  (8192)       fp32
  float* out = (float*)d_out;

  char* ws = (char*)d_ws;
  u64*   keys     = (u64*)  (ws + OFF_KEYS);
  float* partials = (float*)(ws + OFF_PART);

  ranksort_kernel<<<512, 256, 0, stream>>>(L, S, keys);
  wmean_cos_kernel<<<2048, 256, 0, stream>>>(S, keys, partials);
  finalize_kernel <<<1, 256, 0, stream>>>(partials, out);
}

// Round 5
// 78.815 us; speedup vs baseline: 1.0598x; 1.0598x over previous
//
#include <hip/hip_runtime.h>
#include <math.h>

#define BN 8192
#define DN 512
#define KN 8
#define WIN 8           // window half-width around sorted rank (== KN, exact by
                        // the sorted-order argument: 8 nearest are within +-8 ranks)

typedef unsigned long long u64;
typedef unsigned int u32;

// ---- ws layout (bytes) ----
// keys     : u64  [8192] @ 0        (fully sorted (label|idx) keys)
// partials : float[2048] @ 65536
#define OFF_KEYS  0
#define OFF_PART  65536

// Order-preserving float->uint transform (all floats).
__device__ __forceinline__ u32 flip_f32(u32 f) {
  return f ^ (u32)(((int)f >> 31) | 0x80000000);
}
__device__ __forceinline__ float unflip_f32(u32 f) {
  return __uint_as_float((f & 0x80000000u) ? (f ^ 0x80000000u) : ~f);
}

__device__ __forceinline__ u64 shfl_xor_u64(u64 v, int mask) {
  u32 lo = (u32)v, hi = (u32)(v >> 32);
  lo = (u32)__shfl_xor((int)lo, mask, 64);
  hi = (u32)__shfl_xor((int)hi, mask, 64);
  return ((u64)hi << 32) | lo;
}
__device__ __forceinline__ u64 shfl_u64(u64 v, int src) {
  u32 lo = (u32)v, hi = (u32)(v >> 32);
  lo = (u32)__shfl((int)lo, src, 64);
  hi = (u32)__shfl((int)hi, src, 64);
  return ((u64)hi << 32) | lo;
}

// ---------------------------------------------------------------------------
// Kernel A (R1 structure, R5 scan): brute-force rank sort. 512 blocks x 256
// threads. Block stages all 8192 u64 keys in LDS; each wave ranks 4 elements
// by counting smaller keys, scatters keys[rank]=key. Exact sort, no atomics.
// R5: scan reads TWO keys per ds_read_b128 (contiguous 16B/lane) — halves the
// DS instruction count (the scan was LDS-issue-bound: 1024 ds_read_b64/CU
// ~8 cyc each vs 512 ds_read_b128 ~12 cyc). VALU count unchanged.
// (R4 post-mortem: S cache-warm was neutral-negative — removed.)
// ---------------------------------------------------------------------------
__global__ __launch_bounds__(256) void ranksort_kernel(const float* __restrict__ L,
                                                       u64* __restrict__ keys_out) {
  __shared__ u64 kk[BN];                    // 64 KB
  const int tid  = threadIdx.x;
  const int lane = tid & 63;
  const int wv   = tid >> 6;                // 0..3

  // build keys (coalesced label loads; L2-resident after first blocks)
#pragma unroll
  for (int t = 0; t < BN / 256; t++) {
    const int i = tid + t * 256;
    kk[i] = ((u64)flip_f32(__float_as_uint(L[i])) << 32) | (u32)i;
  }
  __syncthreads();

  const int wave_g = blockIdx.x * 4 + wv;   // 0..2047
  const int e0 = wave_g * 4;                // 4 elements per wave
  const u64 k0 = kk[e0 + 0];                // broadcast reads (same addr)
  const u64 k1 = kk[e0 + 1];
  const u64 k2 = kk[e0 + 2];
  const u64 k3 = kk[e0 + 3];

  int c0 = 0, c1 = 0, c2 = 0, c3 = 0;
  // strided scan, 2 keys per ds_read_b128: lane l reads kk[2(l+64t) .. +1]
  const ulonglong2* kk2 = (const ulonglong2*)kk;
#pragma unroll 4
  for (int t = lane; t < BN / 2; t += 64) {
    const ulonglong2 p = kk2[t];
    c0 += (p.x < k0) + (p.y < k0);
    c1 += (p.x < k1) + (p.y < k1);
    c2 += (p.x < k2) + (p.y < k2);
    c3 += (p.x < k3) + (p.y < k3);
  }
#pragma unroll
  for (int off = 1; off < 64; off <<= 1) {
    c0 += __shfl_xor(c0, off, 64);
    c1 += __shfl_xor(c1, off, 64);
    c2 += __shfl_xor(c2, off, 64);
    c3 += __shfl_xor(c3, off, 64);
  }
  if (lane == 0) {                           // ranks are unique -> no conflicts
    keys_out[c0] = k0;
    keys_out[c1] = k1;
    keys_out[c2] = k2;
    keys_out[c3] = k3;
  }
}

// ---------------------------------------------------------------------------
// Kernel B (proven R3, VGPR=32): 2048 blocks x 256 threads, 4 consecutive
// sorted ranks per block (one row per wave; xcd swizzle for L2 locality).
// Window is +-8 sorted ranks (17 candidates, lanes 0..16) -> 15-substep
// 32-wide bitonic. 32 waves/CU hides gather latency via TLP (R4 lesson:
// explicit load hoisting is null at this occupancy).
// Contention-free tail: ONE partials store per block (R2 lesson: 2048-block
// same-address atomic fan-in costs ~60 us on non-coherent L2s).
// ---------------------------------------------------------------------------
__global__ __launch_bounds__(256) void wmean_cos_kernel(const float* __restrict__ S,
                                                        const u64* __restrict__ keys,
                                                        float* __restrict__ partials) {
  const int tid  = threadIdx.x;
  const int lane = tid & 63;
  const int wv   = tid >> 6;                 // 0..3
  const int blk  = blockIdx.x;               // 0..2047
  const int xcd  = blk & 7;
  const int span = blk >> 3;                 // 0..255
  const int rr   = xcd * 1024 + span * 4 + wv;   // this wave's sorted rank

  // candidate window: ranks rr-8 .. rr+8 on lanes 0..16 (L2-resident 64KB)
  const int q = rr - WIN + lane;
  const bool inw = (lane <= 2 * WIN) && (q >= 0) && (q < BN);
  const u64 wk = inw ? keys[q] : ~0ull;

  const u64 ckey = shfl_u64(wk, WIN);        // lane 8 holds rank rr (valid)
  const float Lb = unflip_f32((u32)(ckey >> 32));
  const int   b  = (int)(u32)ckey;

  u64 key = ~0ull;
  if (wk != ~0ull) {                         // real keys never equal ~0ull
    const float lab = unflip_f32((u32)(wk >> 32));
    const float dist = fabsf(lab - Lb);      // >=0: IEEE bits order-preserving
    key = ((u64)__float_as_uint(dist) << 32) | (u32)wk;
  }

  // 32-wide bitonic sort ascending (15 substeps); candidates are in the lower
  // half, lanes 17..31 padded with ~0ull. up=(lane&k)==0 holds for k=32 too.
#pragma unroll
  for (int k = 2; k <= 32; k <<= 1) {
#pragma unroll
    for (int j = 16; j > 0; j >>= 1) {
      if (j >= k) continue;
      const u64 o = shfl_xor_u64(key, j);
      const bool lower = (lane & j) == 0;
      const bool up = (lane & k) == 0;
      key = (up == lower) ? (key < o ? key : o) : (key < o ? o : key);
    }
  }

  // lanes 0..7 hold the 8 nearest; normalized Gaussian weights
  float e = 0.0f;
  if (lane < 8) {
    const float d = __uint_as_float((u32)(key >> 32));
    e = expf(-d * d * (1.0f / 50.0f));       // 2*STD^2 = 50; const cancels
  }
  float ssum = e;
  ssum += __shfl_xor(ssum, 1, 64);
  ssum += __shfl_xor(ssum, 2, 64);
  ssum += __shfl_xor(ssum, 4, 64);
  const float wn = e / ssum;

  int ix[KN]; float w[KN];
  const int myidx = (int)(u32)key;
#pragma unroll
  for (int k = 0; k < KN; k++) {
    ix[k] = __shfl(myidx, k, 64);
    w[k]  = __shfl(wn,    k, 64);
  }

  // gather + weighted mean + cosine
  const float4* Srow = (const float4*)(S + (size_t)b * DN);
  const float4 s0 = Srow[lane];
  const float4 s1 = Srow[lane + 64];

  float4 m0 = make_float4(0.f, 0.f, 0.f, 0.f);
  float4 m1 = make_float4(0.f, 0.f, 0.f, 0.f);
#pragma unroll
  for (int k = 0; k < KN; k++) {
    const float4* Nrow = (const float4*)(S + (size_t)ix[k] * DN);
    const float4 n0 = Nrow[lane];
    const float4 n1 = Nrow[lane + 64];
    const float wk2 = w[k];
    m0.x = fmaf(wk2, n0.x, m0.x); m0.y = fmaf(wk2, n0.y, m0.y);
    m0.z = fmaf(wk2, n0.z, m0.z); m0.w = fmaf(wk2, n0.w, m0.w);
    m1.x = fmaf(wk2, n1.x, m1.x); m1.y = fmaf(wk2, n1.y, m1.y);
    m1.z = fmaf(wk2, n1.z, m1.z); m1.w = fmaf(wk2, n1.w, m1.w);
  }

  float dot = s0.x * m0.x + s0.y * m0.y + s0.z * m0.z + s0.w * m0.w
            + s1.x * m1.x + s1.y * m1.y + s1.z * m1.z + s1.w * m1.w;
  float ns  = s0.x * s0.x + s0.y * s0.y + s0.z * s0.z + s0.w * s0.w
            + s1.x * s1.x + s1.y * s1.y + s1.z * s1.z + s1.w * s1.w;
  float nm  = m0.x * m0.x + m0.y * m0.y + m0.z * m0.z + m0.w * m0.w
            + m1.x * m1.x + m1.y * m1.y + m1.z * m1.z + m1.w * m1.w;

#pragma unroll
  for (int off = 32; off > 0; off >>= 1) {
    dot += __shfl_down(dot, off, 64);
    ns  += __shfl_down(ns,  off, 64);
    nm  += __shfl_down(nm,  off, 64);
  }

  __shared__ float psim[4];
  if (lane == 0) {
    psim[wv] = dot / ((1e-10f + sqrtf(ns)) * (1e-10f + sqrtf(nm)));
  }
  __syncthreads();
  if (tid == 0) {
    partials[blk] = psim[0] + psim[1] + psim[2] + psim[3];
  }
}

// ---------------------------------------------------------------------------
// Kernel C: reduce 2048 partials -> out[0] = 1 - sum/8192.
// ---------------------------------------------------------------------------
__global__ __launch_bounds__(256) void finalize_kernel(const float* __restrict__ partials,
                                                       float* __restrict__ out) {
  const int tid = threadIdx.x;
  float s = 0.0f;
  for (int i = tid; i < 2048; i += 256) s += partials[i];
#pragma unroll
  for (int off = 32; off > 0; off >>= 1) s += __shfl_down(s, off, 64);
  __shared__ float ps[4];
  if ((tid & 63) == 0) ps[tid >> 6] = s;
  __syncthreads();
  if (tid == 0) {
    const float tot = ps[0] + ps[1] + ps[2] + ps[3];
    out[0] = 1.0f - tot * (1.0f / (float)BN);
  }
}

extern "C" void kernel_launch(void* const* d_in, const int* in_sizes, int n_in,
                              void* d_out, int out_size, void* d_ws, size_t ws_size,
                              hipStream_t stream) {
  const float* S = (const float*)d_in[0];  // Struct (8192 x 512) fp32
  const float* L = (const float*)d_in[1];  // Label  (8192)       fp32
  float* out = (float*)d_out;

  char* ws = (char*)d_ws;
  u64*   keys     = (u64*)  (ws + OFF_KEYS);
  float* partials = (float*)(ws + OFF_PART);

  ranksort_kernel<<<512, 256, 0, stream>>>(L, keys);
  wmean_cos_kernel<<<2048, 256, 0, stream>>>(S, keys, partials);
  finalize_kernel <<<1, 256, 0, stream>>>(partials, out);
}